// Round 12
// baseline (227.221 us; speedup 1.0000x reference)
//
#include <hip/hip_runtime.h>
#include <hip/hip_bf16.h>

#define NPTS  1048576
#define GRID  768
#define NTILE 16384  // NPTS / 64

typedef __attribute__((ext_vector_type(8))) short  s16x8;
typedef __attribute__((ext_vector_type(4))) float  f32x4;

// ---------- compile-time least-squares fit of tanh(x) = xs*P(xs^2), xs=x/3 ----------
struct Fit { double c[8]; };
constexpr double cexp(double z) {            // exp(z), |z| <= 8
  double w = z * 0.0625, s = 1.0, t = 1.0;
  for (int i = 1; i < 22; ++i) { t *= w / (double)i; s += t; }
  s = s * s; s = s * s; s = s * s; s = s * s;   // ^16
  return s;
}
constexpr double ctanh(double x) { double e = cexp(2.0 * x); return (e - 1.0) / (e + 1.0); }
constexpr Fit fit_tanh() {
  constexpr int M = 96, N = 8;
  double A[N][N] = {}, b[N] = {};
  for (int j = 0; j < M; ++j) {
    double x  = (j + 0.5) * (3.0 / M);
    double xs = x / 3.0, v = xs * xs;
    double vp[N]; vp[0] = 1.0;
    for (int i = 1; i < N; ++i) vp[i] = vp[i - 1] * v;
    double y = ctanh(x);
    for (int i = 0; i < N; ++i) {
      for (int k = 0; k < N; ++k) A[i][k] += xs * xs * vp[i] * vp[k];
      b[i] += xs * vp[i] * y;
    }
  }
  for (int col = 0; col < N; ++col) {          // Gauss w/ partial pivot
    int piv = col;
    for (int r = col + 1; r < N; ++r) {
      double a1 = A[r][col] < 0 ? -A[r][col] : A[r][col];
      double a2 = A[piv][col] < 0 ? -A[piv][col] : A[piv][col];
      if (a1 > a2) piv = r;
    }
    if (piv != col) {
      for (int k = 0; k < N; ++k) { double t = A[col][k]; A[col][k] = A[piv][k]; A[piv][k] = t; }
      double t = b[col]; b[col] = b[piv]; b[piv] = t;
    }
    for (int r = col + 1; r < N; ++r) {
      double f = A[r][col] / A[col][col];
      for (int k = col; k < N; ++k) A[r][k] -= f * A[col][k];
      b[r] -= f * b[col];
    }
  }
  Fit F{};
  for (int r = N - 1; r >= 0; --r) {
    double s = b[r];
    for (int k = r + 1; k < N; ++k) s -= A[r][k] * F.c[k];
    F.c[r] = s / A[r][r];
  }
  return F;
}
constexpr Fit  FT  = fit_tanh();
constexpr float PC0 = (float)FT.c[0], PC1 = (float)FT.c[1], PC2 = (float)FT.c[2],
                PC3 = (float)FT.c[3], PC4 = (float)FT.c[4], PC5 = (float)FT.c[5],
                PC6 = (float)FT.c[6], PC7 = (float)FT.c[7];

__device__ __forceinline__ float tanh_p(float s) {   // trans-free tanh, 11 VALU ops
  float xs = s * (1.0f / 3.0f);
  xs = __builtin_amdgcn_fmed3f(xs, -1.0f, 1.0f);     // inline-const clamp
  float v = xs * xs;
  float p = PC7;
  p = fmaf(p, v, PC6); p = fmaf(p, v, PC5); p = fmaf(p, v, PC4);
  p = fmaf(p, v, PC3); p = fmaf(p, v, PC2); p = fmaf(p, v, PC1);
  p = fmaf(p, v, PC0);
  return xs * p;
}

__device__ __forceinline__ unsigned short bf16r(float v) {
  unsigned u = __builtin_bit_cast(unsigned, v);
  return (unsigned short)((u + 0x7fffu + ((u >> 16) & 1u)) >> 16);
}
__device__ __forceinline__ unsigned pack_bf16x2(float lo, float hi) {
  __hip_bfloat162 h = __float22bfloat162_rn(float2{lo, hi});
  unsigned r;
  __builtin_memcpy(&r, &h, sizeof(r));
  return r;
}
__device__ __forceinline__ float sigm_fast(float x) {
  return __builtin_amdgcn_rcpf(1.0f + __builtin_amdgcn_exp2f(x * -1.4426950408889634f));
}

// ws layout (u16 units) — W stored TRANSPOSED as MFMA A-fragments (natural n order):
//  [0 .. 49152)     : ws[((l*8 + nbg)*4 + kt)*512 + lane*8 + e] =
//                     bf16( W_{l+2}[k*128 + n] ), k = kt*32 + (lane>>4)*8 + e,
//                     n = nbg*16 + (lane&15);  l=0..2 (W2,W3,W4)
//  [49152 .. 51200) : W5 A-frag image: ws[49152 + kt*512 + lane*8 + e] =
//                     (lane&15)<2 ? bf16(W5[k*2 + (lane&15)]) : 0
__global__ void prep_kernel(const float* __restrict__ W2, const float* __restrict__ W3,
                            const float* __restrict__ W4, const float* __restrict__ W5,
                            unsigned short* __restrict__ ws)
{
  int tid = blockIdx.x * 256 + threadIdx.x;
  if (tid < 49152) {
    int l    = tid >> 14;
    int idx  = tid & 16383;
    int e    = idx & 7;
    int lane = (idx >> 3) & 63;
    int kt   = (idx >> 9) & 3;
    int nbg  = (idx >> 11) & 7;
    int k = kt * 32 + (lane >> 4) * 8 + e;
    int n = nbg * 16 + (lane & 15);
    const float* W = (l == 0) ? W2 : (l == 1) ? W3 : W4;
    ws[tid] = bf16r(W[k * 128 + n]);
  } else if (tid < 51200) {
    int idx  = tid - 49152;
    int e    = idx & 7;
    int lane = (idx >> 3) & 63;
    int kt   = idx >> 9;
    int k  = kt * 32 + (lane >> 4) * 8 + e;
    int nl = lane & 15;
    ws[tid] = (nl < 2) ? bf16r(W5[k * 2 + nl]) : (unsigned short)0;
  }
}

__global__ __launch_bounds__(256, 3)
void mlp_kernel(const float* __restrict__ xy, const float* __restrict__ Uin,
                const float* __restrict__ W1, const float* __restrict__ b1,
                const float* __restrict__ b2, const float* __restrict__ b3,
                const float* __restrict__ b4, const float* __restrict__ b5,
                const unsigned short* __restrict__ ws, float* __restrict__ out)
{
  // ping-pong h buffers, FRAGMENT-MAJOR, 64-point tile (mt=0..3):
  //   hbuf[(mt*4+kt)*1024 + lane*16 + e*2] = h[mt*16+(lane&15)][kt*32+(lane>>4)*8+e]
  __shared__ __align__(16) unsigned char hbuf0[16384];
  __shared__ __align__(16) unsigned char hbuf1[16384];
  __shared__ __align__(16) float         w1tab[384];   // w1x[128],w1y[128],b1[128]
  __shared__ __align__(16) float         bctab[384];   // [l*128+n] = b_{l+2}[n] (plain)
  __shared__ __align__(16) unsigned short b5tab[2048]; // W5 A-frag image

  const int tid  = threadIdx.x;
  const int lane = tid & 63;
  const int wid  = tid >> 6;   // 0..3 : n-column group of 32
  const int lg   = lane >> 4;  // 0..3
  const int ln   = lane & 15;
  const int o    = tid >> 4;   // layer-1 n-octet 0..15
  const int c0   = tid & 15;   // layer-1 point-within-16

  const float Uval = Uin[0];
  const float b50  = b5[0];
  const float b51  = b5[1];

  // ---- stage LDS tables ----
  if (tid < 128) {
    w1tab[tid]       = W1[tid];
    w1tab[128 + tid] = W1[128 + tid];
    w1tab[256 + tid] = b1[tid];
    bctab[tid]       = b2[tid];
    bctab[128 + tid] = b3[tid];
    bctab[256 + tid] = b4[tid];
  }
  ((uint4*)b5tab)[tid] = ((const uint4*)(ws + 49152))[tid];

  // ---- weight A-fragments: opaque asm loads -> cannot be rematerialized ----
  s16x8 Wa[3][2][4];
#pragma unroll
  for (int l = 0; l < 3; ++l)
#pragma unroll
    for (int nb = 0; nb < 2; ++nb)
#pragma unroll
      for (int kt = 0; kt < 4; ++kt) {
        unsigned voff = ((unsigned)(((l * 8 + wid * 2 + nb) * 4 + kt)) << 10)
                      + (unsigned)(lane * 16);
        asm volatile("global_load_dwordx4 %0, %1, %2"
                     : "=v"(Wa[l][nb][kt]) : "v"(voff), "s"(ws));
      }
  asm volatile("s_waitcnt vmcnt(0)");
  __syncthreads();   // tables staged

  // ---- LDS byte bases (all linear, no swizzle) ----
  const unsigned rBase  = (unsigned)(lane * 16);   // + mt*4096 + kt*1024
  const unsigned wBase0 = (unsigned)(wid * 1024 + (lg >> 1) * 256 + ln * 16 + (lg & 1) * 8);
  const unsigned wBase1 = wBase0 + 512;
  const unsigned l1Base = (unsigned)((o >> 2) * 1024 + (o & 3) * 256 + c0 * 16);

  for (int tile = blockIdx.x; tile < NTILE; tile += GRID) {
    const int pbase = tile << 6;

    // ---- layer 1: h1 = tanh(xy@W1+b1) -> hbuf0 ----
    {
      const f32x4 wxa = *(const f32x4*)(w1tab + o * 8);
      const f32x4 wxb = *(const f32x4*)(w1tab + o * 8 + 4);
      const f32x4 wya = *(const f32x4*)(w1tab + 128 + o * 8);
      const f32x4 wyb = *(const f32x4*)(w1tab + 128 + o * 8 + 4);
      const f32x4 bba = *(const f32x4*)(w1tab + 256 + o * 8);
      const f32x4 bbb = *(const f32x4*)(w1tab + 256 + o * 8 + 4);
#pragma unroll
      for (int i = 0; i < 4; ++i) {
        int p = i * 16 + c0;
        float2 v = ((const float2*)xy)[pbase + p];
        unsigned q[4];
#pragma unroll
        for (int t2 = 0; t2 < 2; ++t2) {
          float s0 = fmaf(v.x, wxa[2 * t2],     fmaf(v.y, wya[2 * t2],     bba[2 * t2]));
          float s1 = fmaf(v.x, wxa[2 * t2 + 1], fmaf(v.y, wya[2 * t2 + 1], bba[2 * t2 + 1]));
          q[t2] = pack_bf16x2(tanh_p(s0), tanh_p(s1));
        }
#pragma unroll
        for (int t2 = 0; t2 < 2; ++t2) {
          float s0 = fmaf(v.x, wxb[2 * t2],     fmaf(v.y, wyb[2 * t2],     bbb[2 * t2]));
          float s1 = fmaf(v.x, wxb[2 * t2 + 1], fmaf(v.y, wyb[2 * t2 + 1], bbb[2 * t2 + 1]));
          q[2 + t2] = pack_bf16x2(tanh_p(s0), tanh_p(s1));
        }
        *(uint4*)(hbuf0 + l1Base + i * 4096) = uint4{q[0], q[1], q[2], q[3]};
      }
    }
    __syncthreads();   // h1 visible

    // ---- layers 2..4: D = W^T · h^T (weights = pinned A operand; bias in acc) ----
#pragma unroll
    for (int l = 0; l < 3; ++l) {
      const unsigned char* bufR = (l & 1) ? hbuf1 : hbuf0;
      unsigned char*       bufW = (l & 1) ? hbuf0 : hbuf1;
      const f32x4 bcl0 = *(const f32x4*)(bctab + l * 128 + wid * 32 + lg * 4);
      const f32x4 bcl1 = *(const f32x4*)(bctab + l * 128 + wid * 32 + 16 + lg * 4);
#pragma unroll
      for (int mt = 0; mt < 4; ++mt) {
        s16x8 B[4];
#pragma unroll
        for (int kt = 0; kt < 4; ++kt)
          B[kt] = *(const s16x8*)(bufR + rBase + mt * 4096 + kt * 1024);
        f32x4 acc0 = bcl0;   // bias folded into MFMA C-operand
        f32x4 acc1 = bcl1;
#pragma unroll
        for (int kt = 0; kt < 4; ++kt) {
          acc0 = __builtin_amdgcn_mfma_f32_16x16x32_bf16(Wa[l][0][kt], B[kt], acc0, 0, 0, 0);
          acc1 = __builtin_amdgcn_mfma_f32_16x16x32_bf16(Wa[l][1][kt], B[kt], acc1, 0, 0, 0);
        }
        {
          float t0 = tanh_p(acc0[0]);
          float t1 = tanh_p(acc0[1]);
          float t2 = tanh_p(acc0[2]);
          float t3 = tanh_p(acc0[3]);
          *(uint2*)(bufW + wBase0 + mt * 4096) = uint2{pack_bf16x2(t0, t1), pack_bf16x2(t2, t3)};
        }
        {
          float t0 = tanh_p(acc1[0]);
          float t1 = tanh_p(acc1[1]);
          float t2 = tanh_p(acc1[2]);
          float t3 = tanh_p(acc1[3]);
          *(uint2*)(bufW + wBase1 + mt * 4096) = uint2{pack_bf16x2(t0, t1), pack_bf16x2(t2, t3)};
        }
      }
      __syncthreads();
    }

    // ---- layer 5 + epilogue (reads hbuf1 = L4 out; wave: 16 points, mt=wid) ----
    f32x4 acc5 = f32x4{0.f, 0.f, 0.f, 0.f};
#pragma unroll
    for (int kt = 0; kt < 4; ++kt) {
      s16x8 b5f = *(const s16x8*)(b5tab + kt * 512 + lane * 8);
      s16x8 b   = *(const s16x8*)(hbuf1 + rBase + wid * 4096 + kt * 1024);
      acc5 = __builtin_amdgcn_mfma_f32_16x16x32_bf16(b5f, b, acc5, 0, 0, 0);
    }
    if (lg == 0) {
      int p = pbase + wid * 16 + ln;
      float uh = acc5[0] + b50;
      float vh = acc5[1] + b51;
      float2 v = ((const float2*)xy)[p];
      float Bm = v.x * (1.0f - v.x) * v.y * (1.0f - v.y);
      float psi = sigm_fast(50.0f * (v.x - 0.05f)) * sigm_fast(50.0f * (0.95f - v.x));
      out[p]        = fmaf(Uval * v.y, psi, Bm * uh);
      out[NPTS + p] = Bm * vh;
    }
    // no trailing barrier: next L1 writes hbuf0 (last readers l=2 are behind the
    // l=2 barrier); next l=0 writes hbuf1 after the post-L1 barrier, after L5 reads.
  }
}

extern "C" void kernel_launch(void* const* d_in, const int* in_sizes, int n_in,
                              void* d_out, int out_size, void* d_ws, size_t ws_size,
                              hipStream_t stream) {
  const float* xy = (const float*)d_in[0];
  const float* U  = (const float*)d_in[1];
  const float* W1 = (const float*)d_in[2];
  const float* b1 = (const float*)d_in[3];
  const float* W2 = (const float*)d_in[4];
  const float* b2 = (const float*)d_in[5];
  const float* W3 = (const float*)d_in[6];
  const float* b3 = (const float*)d_in[7];
  const float* W4 = (const float*)d_in[8];
  const float* b4 = (const float*)d_in[9];
  const float* W5 = (const float*)d_in[10];
  const float* b5 = (const float*)d_in[11];
  unsigned short* ws = (unsigned short*)d_ws;   // needs ~100 KB
  float* out = (float*)d_out;

  prep_kernel<<<200, 256, 0, stream>>>(W2, W3, W4, W5, ws);
  mlp_kernel<<<GRID, 256, 0, stream>>>(xy, U, W1, b1, b2, b3, b4, b5, ws, out);
}

// Round 13
// 199.128 us; speedup vs baseline: 1.1411x; 1.1411x over previous
//
#include <hip/hip_runtime.h>
#include <hip/hip_bf16.h>

#define NPTS  1048576
#define GRID  768
#define NTILE 16384  // NPTS / 64
#define C2    2.8853900817779268f   // 2*log2(e)

typedef __attribute__((ext_vector_type(8))) short  s16x8;
typedef __attribute__((ext_vector_type(4))) float  f32x4;

__device__ __forceinline__ unsigned short bf16r(float v) {
  unsigned u = __builtin_bit_cast(unsigned, v);
  return (unsigned short)((u + 0x7fffu + ((u >> 16) & 1u)) >> 16);
}
__device__ __forceinline__ unsigned pack_bf16x2(float lo, float hi) {
  __hip_bfloat162 h = __float22bfloat162_rn(float2{lo, hi});
  unsigned r;
  __builtin_memcpy(&r, &h, sizeof(r));
  return r;
}
// tanh(s) with bias pre-folded: bc = bias*C2  (trans ops are ~full-rate on gfx950)
__device__ __forceinline__ float tanh_e(float acc, float bc) {
  float e = __builtin_amdgcn_exp2f(fmaf(acc, C2, bc));
  return 1.0f - 2.0f * __builtin_amdgcn_rcpf(1.0f + e);
}
__device__ __forceinline__ float sigm_fast(float x) {
  return __builtin_amdgcn_rcpf(1.0f + __builtin_amdgcn_exp2f(x * -1.4426950408889634f));
}

// ws layout (u16 units) — W stored TRANSPOSED as MFMA A-fragments (natural n order):
//  [0 .. 49152)     : ws[((l*8 + nbg)*4 + kt)*512 + lane*8 + e] =
//                     bf16( W_{l+2}[k*128 + n] ), k = kt*32 + (lane>>4)*8 + e,
//                     n = nbg*16 + (lane&15);  l=0..2 (W2,W3,W4)
//  [49152 .. 51200) : W5 A-frag image: ws[49152 + kt*512 + lane*8 + e] =
//                     (lane&15)<2 ? bf16(W5[k*2 + (lane&15)]) : 0
__global__ void prep_kernel(const float* __restrict__ W2, const float* __restrict__ W3,
                            const float* __restrict__ W4, const float* __restrict__ W5,
                            unsigned short* __restrict__ ws)
{
  int tid = blockIdx.x * 256 + threadIdx.x;
  if (tid < 49152) {
    int l    = tid >> 14;
    int idx  = tid & 16383;
    int e    = idx & 7;
    int lane = (idx >> 3) & 63;
    int kt   = (idx >> 9) & 3;
    int nbg  = (idx >> 11) & 7;
    int k = kt * 32 + (lane >> 4) * 8 + e;
    int n = nbg * 16 + (lane & 15);
    const float* W = (l == 0) ? W2 : (l == 1) ? W3 : W4;
    ws[tid] = bf16r(W[k * 128 + n]);
  } else if (tid < 51200) {
    int idx  = tid - 49152;
    int e    = idx & 7;
    int lane = (idx >> 3) & 63;
    int kt   = idx >> 9;
    int k  = kt * 32 + (lane >> 4) * 8 + e;
    int nl = lane & 15;
    ws[tid] = (nl < 2) ? bf16r(W5[k * 2 + nl]) : (unsigned short)0;
  }
}

// one hidden layer: D = W^T·h^T, tanh, write back. WA bound statically via inlining.
__device__ __forceinline__ void layer_fwd(const s16x8 WA[2][4],
                                          const unsigned char* bufR, unsigned char* bufW,
                                          const float* bctab_l,
                                          unsigned rBase, unsigned wBase0, unsigned wBase1,
                                          int wid, int lg)
{
  const f32x4 bcl0 = *(const f32x4*)(bctab_l + wid * 32 + lg * 4);
  const f32x4 bcl1 = *(const f32x4*)(bctab_l + wid * 32 + 16 + lg * 4);
#pragma unroll
  for (int mt = 0; mt < 4; ++mt) {
    s16x8 B[4];
#pragma unroll
    for (int kt = 0; kt < 4; ++kt)
      B[kt] = *(const s16x8*)(bufR + rBase + mt * 4096 + kt * 1024);
    f32x4 acc0 = f32x4{0.f, 0.f, 0.f, 0.f};
    f32x4 acc1 = f32x4{0.f, 0.f, 0.f, 0.f};
#pragma unroll
    for (int kt = 0; kt < 4; ++kt) {
      acc0 = __builtin_amdgcn_mfma_f32_16x16x32_bf16(WA[0][kt], B[kt], acc0, 0, 0, 0);
      acc1 = __builtin_amdgcn_mfma_f32_16x16x32_bf16(WA[1][kt], B[kt], acc1, 0, 0, 0);
    }
    {
      float t0 = tanh_e(acc0[0], bcl0[0]);
      float t1 = tanh_e(acc0[1], bcl0[1]);
      float t2 = tanh_e(acc0[2], bcl0[2]);
      float t3 = tanh_e(acc0[3], bcl0[3]);
      *(uint2*)(bufW + wBase0 + mt * 4096) = uint2{pack_bf16x2(t0, t1), pack_bf16x2(t2, t3)};
    }
    {
      float t0 = tanh_e(acc1[0], bcl1[0]);
      float t1 = tanh_e(acc1[1], bcl1[1]);
      float t2 = tanh_e(acc1[2], bcl1[2]);
      float t3 = tanh_e(acc1[3], bcl1[3]);
      *(uint2*)(bufW + wBase1 + mt * 4096) = uint2{pack_bf16x2(t0, t1), pack_bf16x2(t2, t3)};
    }
  }
}

__global__ __launch_bounds__(256, 3)
void mlp_kernel(const float* __restrict__ xy, const float* __restrict__ Uin,
                const float* __restrict__ W1, const float* __restrict__ b1,
                const float* __restrict__ b2, const float* __restrict__ b3,
                const float* __restrict__ b4, const float* __restrict__ b5,
                const unsigned short* __restrict__ ws, float* __restrict__ out)
{
  // ping-pong h buffers, FRAGMENT-MAJOR, 64-point tile (mt=0..3):
  //   hbuf[(mt*4+kt)*1024 + lane*16 + e*2] = h[mt*16+(lane&15)][kt*32+(lane>>4)*8+e]
  __shared__ __align__(16) unsigned char hbuf0[16384];
  __shared__ __align__(16) unsigned char hbuf1[16384];
  __shared__ __align__(16) float         w1tab[384];   // w1x[128],w1y[128],b1[128]
  __shared__ __align__(16) float         bctab[384];   // [l*128+n] = b_{l+2}[n]*C2
  __shared__ __align__(16) unsigned short b5tab[2048]; // W5 A-frag image

  const int tid  = threadIdx.x;
  const int lane = tid & 63;
  const int wid  = tid >> 6;   // 0..3 : n-column group of 32
  const int lg   = lane >> 4;  // 0..3
  const int ln   = lane & 15;
  const int o    = tid >> 4;   // layer-1 n-octet 0..15
  const int c0   = tid & 15;   // layer-1 point-within-16

  const float Uval = Uin[0];
  const float b50  = b5[0];
  const float b51  = b5[1];

  // ---- stage LDS tables ----
  if (tid < 128) {
    w1tab[tid]       = W1[tid];
    w1tab[128 + tid] = W1[128 + tid];
    w1tab[256 + tid] = b1[tid];
    bctab[tid]       = b2[tid] * C2;
    bctab[128 + tid] = b3[tid] * C2;
    bctab[256 + tid] = b4[tid] * C2;
  }
  ((uint4*)b5tab)[tid] = ((const uint4*)(ws + 49152))[tid];

  // ---- W3,W4 A-fragments: opaque asm loads, pinned for the whole kernel ----
  s16x8 Wa3[2][4], Wa4[2][4];
#pragma unroll
  for (int nb = 0; nb < 2; ++nb)
#pragma unroll
    for (int kt = 0; kt < 4; ++kt) {
      unsigned voff3 = ((unsigned)(((1 * 8 + wid * 2 + nb) * 4 + kt)) << 10) + (unsigned)(lane * 16);
      unsigned voff4 = ((unsigned)(((2 * 8 + wid * 2 + nb) * 4 + kt)) << 10) + (unsigned)(lane * 16);
      asm volatile("global_load_dwordx4 %0, %1, %2"
                   : "=v"(Wa3[nb][kt]) : "v"(voff3), "s"(ws));
      asm volatile("global_load_dwordx4 %0, %1, %2"
                   : "=v"(Wa4[nb][kt]) : "v"(voff4), "s"(ws));
    }
  asm volatile("s_waitcnt vmcnt(0)");
  __builtin_amdgcn_sched_barrier(0);
  __syncthreads();   // tables staged

  // ---- LDS byte bases (all linear, no swizzle) ----
  const unsigned rBase  = (unsigned)(lane * 16);   // + mt*4096 + kt*1024
  const unsigned wBase0 = (unsigned)(wid * 1024 + (lg >> 1) * 256 + ln * 16 + (lg & 1) * 8);
  const unsigned wBase1 = wBase0 + 512;
  const unsigned l1Base = (unsigned)((o >> 2) * 1024 + (o & 3) * 256 + c0 * 16);

  for (int tile = blockIdx.x; tile < NTILE; tile += GRID) {
    const int pbase = tile << 6;

    // ---- stream this tile's W2 fragments (L1/L2-resident; latency hides under L1) ----
    s16x8 W2f[2][4];
#pragma unroll
    for (int nb = 0; nb < 2; ++nb)
#pragma unroll
      for (int kt = 0; kt < 4; ++kt)
        W2f[nb][kt] = *(const s16x8*)(ws + (((0 * 8 + wid * 2 + nb) * 4 + kt) << 9) + lane * 8);

    // ---- layer 1: h1 = tanh(xy@W1+b1) -> hbuf0 ----
    {
      const f32x4 wxa = *(const f32x4*)(w1tab + o * 8);
      const f32x4 wxb = *(const f32x4*)(w1tab + o * 8 + 4);
      const f32x4 wya = *(const f32x4*)(w1tab + 128 + o * 8);
      const f32x4 wyb = *(const f32x4*)(w1tab + 128 + o * 8 + 4);
      const f32x4 bba = *(const f32x4*)(w1tab + 256 + o * 8);
      const f32x4 bbb = *(const f32x4*)(w1tab + 256 + o * 8 + 4);
#pragma unroll
      for (int i = 0; i < 4; ++i) {
        int p = i * 16 + c0;
        float2 v = ((const float2*)xy)[pbase + p];
        unsigned q[4];
#pragma unroll
        for (int t2 = 0; t2 < 2; ++t2) {
          float s0 = fmaf(v.x, wxa[2 * t2],     fmaf(v.y, wya[2 * t2],     bba[2 * t2]));
          float s1 = fmaf(v.x, wxa[2 * t2 + 1], fmaf(v.y, wya[2 * t2 + 1], bba[2 * t2 + 1]));
          float e0 = __builtin_amdgcn_exp2f(s0 * C2);
          float e1 = __builtin_amdgcn_exp2f(s1 * C2);
          q[t2] = pack_bf16x2(1.0f - 2.0f * __builtin_amdgcn_rcpf(1.0f + e0),
                              1.0f - 2.0f * __builtin_amdgcn_rcpf(1.0f + e1));
        }
#pragma unroll
        for (int t2 = 0; t2 < 2; ++t2) {
          float s0 = fmaf(v.x, wxb[2 * t2],     fmaf(v.y, wyb[2 * t2],     bbb[2 * t2]));
          float s1 = fmaf(v.x, wxb[2 * t2 + 1], fmaf(v.y, wyb[2 * t2 + 1], bbb[2 * t2 + 1]));
          float e0 = __builtin_amdgcn_exp2f(s0 * C2);
          float e1 = __builtin_amdgcn_exp2f(s1 * C2);
          q[2 + t2] = pack_bf16x2(1.0f - 2.0f * __builtin_amdgcn_rcpf(1.0f + e0),
                                  1.0f - 2.0f * __builtin_amdgcn_rcpf(1.0f + e1));
        }
        *(uint4*)(hbuf0 + l1Base + i * 4096) = uint4{q[0], q[1], q[2], q[3]};
      }
    }
    __syncthreads();   // h1 visible (also drains W2f loads)

    // ---- layers 2..4 ----
    layer_fwd(W2f, hbuf0, hbuf1, bctab,       rBase, wBase0, wBase1, wid, lg);
    __syncthreads();
    layer_fwd(Wa3, hbuf1, hbuf0, bctab + 128, rBase, wBase0, wBase1, wid, lg);
    __syncthreads();
    layer_fwd(Wa4, hbuf0, hbuf1, bctab + 256, rBase, wBase0, wBase1, wid, lg);
    __syncthreads();

    // ---- layer 5 + epilogue (reads hbuf1 = L4 out; wave: 16 points, mt=wid) ----
    f32x4 acc5 = f32x4{0.f, 0.f, 0.f, 0.f};
#pragma unroll
    for (int kt = 0; kt < 4; ++kt) {
      s16x8 b5f = *(const s16x8*)(b5tab + kt * 512 + lane * 8);
      s16x8 b   = *(const s16x8*)(hbuf1 + rBase + wid * 4096 + kt * 1024);
      acc5 = __builtin_amdgcn_mfma_f32_16x16x32_bf16(b5f, b, acc5, 0, 0, 0);
    }
    if (lg == 0) {
      int p = pbase + wid * 16 + ln;
      float uh = acc5[0] + b50;
      float vh = acc5[1] + b51;
      float2 v = ((const float2*)xy)[p];
      float Bm = v.x * (1.0f - v.x) * v.y * (1.0f - v.y);
      float psi = sigm_fast(50.0f * (v.x - 0.05f)) * sigm_fast(50.0f * (0.95f - v.x));
      out[p]        = fmaf(Uval * v.y, psi, Bm * uh);
      out[NPTS + p] = Bm * vh;
    }
    // no trailing barrier: next L1 writes hbuf0 (last readers are behind the L4
    // barrier); next L2 writes hbuf1 after the post-L1 barrier, after L5 reads.
  }
}

extern "C" void kernel_launch(void* const* d_in, const int* in_sizes, int n_in,
                              void* d_out, int out_size, void* d_ws, size_t ws_size,
                              hipStream_t stream) {
  const float* xy = (const float*)d_in[0];
  const float* U  = (const float*)d_in[1];
  const float* W1 = (const float*)d_in[2];
  const float* b1 = (const float*)d_in[3];
  const float* W2 = (const float*)d_in[4];
  const float* b2 = (const float*)d_in[5];
  const float* W3 = (const float*)d_in[6];
  const float* b3 = (const float*)d_in[7];
  const float* W4 = (const float*)d_in[8];
  const float* b4 = (const float*)d_in[9];
  const float* W5 = (const float*)d_in[10];
  const float* b5 = (const float*)d_in[11];
  unsigned short* ws = (unsigned short*)d_ws;   // needs ~100 KB
  float* out = (float*)d_out;

  prep_kernel<<<200, 256, 0, stream>>>(W2, W3, W4, W5, ws);
  mlp_kernel<<<GRID, 256, 0, stream>>>(xy, U, W1, b1, b2, b3, b4, b5, ws, out);
}